// Round 12
// baseline (441.835 us; speedup 1.0000x reference)
//
#include <hip/hip_runtime.h>
#include <hip/hip_bf16.h>

typedef __hip_bfloat16 bf16;
#define SLOPE 0.2f

__device__ __forceinline__ float b2f(bf16 v) { return __bfloat162float(v); }
__device__ __forceinline__ short f2b_raw(float x) {
    bf16 b = __float2bfloat16(x);
    return *reinterpret_cast<short*>(&b);
}

typedef __attribute__((ext_vector_type(8))) short bf16x8;
typedef __attribute__((ext_vector_type(16))) float f32x16;
typedef __attribute__((ext_vector_type(2))) float f32x2;

union Q16 { uint4 q[2]; unsigned u[8]; };

// ---------------- merged prep: dtype detect, weight pack, HIST (cnt pre-zeroed by memset),
// ticket/done zero ----
__global__ void k_prep(const void* __restrict__ x,
                       const void* __restrict__ W0, const void* __restrict__ W1,
                       const void* __restrict__ W2, const void* __restrict__ Wr2,
                       const void* __restrict__ a0, const void* __restrict__ a1,
                       const void* __restrict__ a2, bf16* __restrict__ W0p,
                       bf16* __restrict__ W1p, bf16* __restrict__ W2fp,
                       bf16* __restrict__ a0c, bf16* __restrict__ a1c,
                       bf16* __restrict__ a2c, int* __restrict__ flag,
                       int* __restrict__ ticket, int* __restrict__ done,
                       const int* __restrict__ dste, int* __restrict__ cnt, int E) {
    __shared__ int sflag;
    if (threadIdx.x < 64) {
        const unsigned short* u = (const unsigned short*)x;
        int tid = threadIdx.x;
        int nice = 0;
        for (int k = tid; k < 256; k += 64) {
            unsigned int bits = ((unsigned int)u[2 * k]) << 16;
            float v = __uint_as_float(bits);
            float av = fabsf(v);
            if (v == 0.0f || (av > 1e-6f && av < 100.0f)) ++nice;
        }
        for (int off = 32; off > 0; off >>= 1) nice += __shfl_down(nice, off, 64);
        if (tid == 0) sflag = (nice >= 192) ? 0 : 1;
    }
    __syncthreads();
    int isf = sflag;
    int idx = blockIdx.x * blockDim.x + threadIdx.x;
    if (blockIdx.x == 0 && threadIdx.x == 0) { *flag = isf; *ticket = 0; *done = 0; }
    // histogram of dst (cnt was zeroed by the preceding memset on this stream)
    if (idx < E) atomicAdd(&cnt[dste[idx]], 1);
    if (idx < 131072) {
        int t = idx & 65535;
        int j = t & 7, L = (t >> 3) & 63, kt = (t >> 9) & 15, nt = t >> 13;
        int n = nt * 32 + (L & 31);
        int k = kt * 16 + (L >> 5) * 8 + j;
        const void* src = (idx < 65536) ? W0 : W1;
        float v = isf ? ((const float*)src)[k * 256 + n] : b2f(((const bf16*)src)[k * 256 + n]);
        bf16* dstp = (idx < 65536) ? W0p : W1p;
        dstp[t] = __float2bfloat16(v);
    } else if (idx < 147456) {
        int t = idx - 131072;
        int j = t & 7, L = (t >> 3) & 63, kt = (t >> 9) & 15, nt = t >> 13;
        int n = nt * 32 + (L & 31);
        int k = kt * 16 + (L >> 5) * 8 + j;
        const void* src = (n < 32) ? W2 : Wr2;
        int nn = n & 31;
        float v = isf ? ((const float*)src)[k * 32 + nn] : b2f(((const bf16*)src)[k * 32 + nn]);
        W2fp[t] = __float2bfloat16(v);
    } else if (idx < 147456 + 256) {
        int t = idx - 147456;
        float v = isf ? ((const float*)a0)[t] : b2f(((const bf16*)a0)[t]);
        a0c[t] = __float2bfloat16(v);
    } else if (idx < 147456 + 512) {
        int t = idx - 147456 - 256;
        float v = isf ? ((const float*)a1)[t] : b2f(((const bf16*)a1)[t]);
        a1c[t] = __float2bfloat16(v);
    } else if (idx < 147456 + 544) {
        int t = idx - 147456 - 512;
        float v = isf ? ((const float*)a2)[t] : b2f(((const bf16*)a2)[t]);
        a2c[t] = __float2bfloat16(v);
    }
}

// ---------------- fused scan: per-block sums + decoupled scan + rowptr/cursor write ----
// Grid is exactly B = ceil(N/1024) <= 64 blocks -> all co-resident, spin is safe.
__global__ void k_scan_fused(const int* __restrict__ cnt, int* __restrict__ bsum,
                             int* __restrict__ bscan, int* __restrict__ ticket,
                             int* __restrict__ done, int* __restrict__ rowptr,
                             int* __restrict__ cursor, int n, int E, int B) {
    __shared__ int sh[256];
    __shared__ int sbase;
    int base = blockIdx.x * 1024 + threadIdx.x * 4;
    int loc[4];
    int s = 0;
#pragma unroll
    for (int k = 0; k < 4; ++k) {
        int i = base + k;
        loc[k] = (i < n) ? cnt[i] : 0;
        s += loc[k];
    }
    sh[threadIdx.x] = s;
    __syncthreads();
    for (int off = 1; off < 256; off <<= 1) {
        int u = (threadIdx.x >= off) ? sh[threadIdx.x - off] : 0;
        __syncthreads();
        sh[threadIdx.x] += u;
        __syncthreads();
    }
    if (threadIdx.x == 0) {
        atomicExch(&bsum[blockIdx.x], sh[255]);
        __threadfence();
        int t = atomicAdd(ticket, 1);
        sbase = (t == B - 1) ? 1 : 0;  // reuse sbase as "am I last" temporarily
    }
    __syncthreads();
    if (sbase && threadIdx.x < 64) {
        int tid = threadIdx.x;
        int v = (tid < B) ? atomicAdd(&bsum[tid], 0) : 0;
        int xv = v;
#pragma unroll
        for (int off = 1; off < 64; off <<= 1) {
            int y = __shfl_up(xv, off, 64);
            if (tid >= off) xv += y;
        }
        if (tid < B) atomicExch(&bscan[tid], xv - v);
        __threadfence();
        if (tid == 0) atomicExch(done, 1);
    }
    if (threadIdx.x == 0) {
        while (atomicAdd(done, 0) == 0) {}
        sbase = atomicAdd(&bscan[blockIdx.x], 0);
    }
    __syncthreads();
    int run = sbase + sh[threadIdx.x] - s;
#pragma unroll
    for (int k = 0; k < 4; ++k) {
        int i = base + k;
        if (i < n) { rowptr[i] = run; cursor[i] = run; run += loc[k]; }
    }
    if (blockIdx.x == 0 && threadIdx.x == 0) rowptr[n] = E;
}

__global__ void k_scatter(const int* __restrict__ src, const int* __restrict__ dst,
                          int* __restrict__ cursor, int* __restrict__ csr_src, int E) {
    int e = blockIdx.x * blockDim.x + threadIdx.x;
    if (e < E) {
        int p = atomicAdd(&cursor[dst[e]], 1);
        csr_src[p] = src[e];
    }
    if (e < 32) csr_src[E + e] = 0;  // sentinel padding for clamp-free prefetch
}

// ---------------- MFMA GEMM: C[N,256](bf16) = A[N,256] @ W; B pre-packed fragments ----
template <int ADAPT>
__global__ void k_gemm_mfma(const void* __restrict__ A, const bf16* __restrict__ Wp,
                            bf16* __restrict__ C, int Nrows, const int* __restrict__ flag) {
    int warp = threadIdx.x >> 6;
    int lane = threadIdx.x & 63;
    int wr = warp >> 1;
    int wc = warp & 1;
    long rowBase = (long)blockIdx.x * 64 + wr * 32;
    int colBase = wc * 128;
    int m = lane & 31;
    int g = lane >> 5;
    long r = rowBase + m;
    if (r >= Nrows) r = Nrows - 1;
    int isf32 = ADAPT ? *flag : 0;
    const short* Ab = (const short*)A + r * 256 + g * 8;
    const float* Af = (const float*)A + r * 256 + g * 8;
    const short* Wps = (const short*)Wp;
    f32x16 acc[4] = {};
    for (int kt = 0; kt < 16; ++kt) {
        bf16x8 af;
        if (ADAPT && isf32) {
            float4 x0 = *(const float4*)(Af + kt * 16);
            float4 x1 = *(const float4*)(Af + kt * 16 + 4);
            union { bf16x8 v; short s[8]; } t;
            t.s[0] = f2b_raw(x0.x); t.s[1] = f2b_raw(x0.y);
            t.s[2] = f2b_raw(x0.z); t.s[3] = f2b_raw(x0.w);
            t.s[4] = f2b_raw(x1.x); t.s[5] = f2b_raw(x1.y);
            t.s[6] = f2b_raw(x1.z); t.s[7] = f2b_raw(x1.w);
            af = t.v;
        } else {
            af = *(const bf16x8*)(Ab + kt * 16);
        }
#pragma unroll
        for (int ct = 0; ct < 4; ++ct) {
            int nt = wc * 4 + ct;
            bf16x8 bfr = *(const bf16x8*)(Wps + (((nt << 4) + kt) << 9) + lane * 8);
            acc[ct] = __builtin_amdgcn_mfma_f32_32x32x16_bf16(af, bfr, acc[ct], 0, 0, 0);
        }
    }
#pragma unroll
    for (int ct = 0; ct < 4; ++ct) {
#pragma unroll
        for (int i = 0; i < 16; ++i) {
            long row = rowBase + (i & 3) + 8 * (i >> 2) + 4 * g;
            if (row < Nrows)
                C[row * 256 + colBase + ct * 32 + m] = __float2bfloat16(acc[ct][i]);
        }
    }
}

// C[N,64] = A[N,256](bf16) @ combined final weights (fragment-packed)
__global__ void k_gemm_mfma64(const bf16* __restrict__ A, const bf16* __restrict__ Wp,
                              bf16* __restrict__ C, int Nrows) {
    int warp = threadIdx.x >> 6;
    int lane = threadIdx.x & 63;
    long rowBase = (long)blockIdx.x * 128 + warp * 32;
    int m = lane & 31;
    int g = lane >> 5;
    long r = rowBase + m;
    if (r >= Nrows) r = Nrows - 1;
    const short* Arow = (const short*)A + r * 256 + g * 8;
    const short* Wps = (const short*)Wp;
    f32x16 acc[2] = {};
    for (int kt = 0; kt < 16; ++kt) {
        bf16x8 af = *(const bf16x8*)(Arow + kt * 16);
#pragma unroll
        for (int ct = 0; ct < 2; ++ct) {
            bf16x8 bfr = *(const bf16x8*)(Wps + (((ct << 4) + kt) << 9) + lane * 8);
            acc[ct] = __builtin_amdgcn_mfma_f32_32x32x16_bf16(af, bfr, acc[ct], 0, 0, 0);
        }
    }
#pragma unroll
    for (int ct = 0; ct < 2; ++ct) {
#pragma unroll
        for (int i = 0; i < 16; ++i) {
            long row = rowBase + (i & 3) + 8 * (i >> 2) + 4 * g;
            if (row < Nrows)
                C[row * 64 + ct * 32 + m] = __float2bfloat16(acc[ct][i]);
        }
    }
}

// ---------------- Fused GATv2 layer: 8 edges/iter (2 per slot), 16 lanes/edge ----------
// Round-11 proven body; csr_src is padded so no min() clamps needed.
__global__ void k_gat_fused(const uint4* __restrict__ f, const bf16* __restrict__ a,
                            const int* __restrict__ rowptr, const int* __restrict__ csr_src,
                            const uint4* __restrict__ res, uint4* __restrict__ out,
                            int N, int mode) {
    int n = (blockIdx.x * blockDim.x + threadIdx.x) >> 6;
    int lane = threadIdx.x & 63;
    if (n >= N) return;
    int j = lane >> 4, l = lane & 15;

    Q16 fdq, aq;
    fdq.q[0] = f[(long)n * 32 + 2 * l];
    fdq.q[1] = f[(long)n * 32 + 2 * l + 1];
    aq.q[0] = ((const uint4*)a)[2 * l];
    aq.q[1] = ((const uint4*)a)[2 * l + 1];
    f32x2 fd2[8], a6[8], a4[8];
#pragma unroll
    for (int i = 0; i < 8; ++i) {
        f32x2 fv, av;
        fv.x = __uint_as_float(fdq.u[i] << 16);
        fv.y = __uint_as_float(fdq.u[i] & 0xffff0000u);
        av.x = __uint_as_float(aq.u[i] << 16);
        av.y = __uint_as_float(aq.u[i] & 0xffff0000u);
        fd2[i] = fv;
        a6[i] = 0.6f * av;
        a4[i] = 0.4f * av;
    }

    int p0 = rowptr[n], p1 = rowptr[n + 1];
    int iters = (p1 - p0 + 3) >> 2;
    float z = 0.f;
    f32x2 acc[8] = {};

    int p = p0 + j;
    Q16 A0, A1, B0, B1;
    {
        int s0 = csr_src[p];
        A0.q[0] = f[(long)s0 * 32 + 2 * l];
        A0.q[1] = f[(long)s0 * 32 + 2 * l + 1];
        int s1 = csr_src[p + 4];
        A1.q[0] = f[(long)s1 * 32 + 2 * l];
        A1.q[1] = f[(long)s1 * 32 + 2 * l + 1];
    }
    for (int i = 0; i < iters; i += 2) {
        int s0 = csr_src[p + 8];
        B0.q[0] = f[(long)s0 * 32 + 2 * l];
        B0.q[1] = f[(long)s0 * 32 + 2 * l + 1];
        int s1 = csr_src[p + 12];
        B1.q[0] = f[(long)s1 * 32 + 2 * l];
        B1.q[1] = f[(long)s1 * 32 + 2 * l + 1];

#pragma unroll
        for (int half = 0; half < 2; ++half) {
            if (half == 1 && i + 1 >= iters) break;
            const Q16& cur = half ? A1 : A0;
            int pp = p + half * 4;
            f32x2 fs[8];
            f32x2 t2 = {0.f, 0.f};
#pragma unroll
            for (int k = 0; k < 8; ++k) {
                f32x2 fv;
                fv.x = __uint_as_float(cur.u[k] << 16);
                fv.y = __uint_as_float(cur.u[k] & 0xffff0000u);
                fs[k] = fv;
                f32x2 u = fv + fd2[k];
                f32x2 ua;
                ua.x = __uint_as_float(__float_as_uint(u.x) & 0x7fffffffu);
                ua.y = __uint_as_float(__float_as_uint(u.y) & 0x7fffffffu);
                t2 = a6[k] * u + t2;
                t2 = a4[k] * ua + t2;
            }
            float t = t2.x + t2.y;
            t += __shfl_xor(t, 1);
            t += __shfl_xor(t, 2);
            float wgt = (pp < p1) ? __expf(t) : 0.f;
            z += wgt;
            f32x2 w2 = {wgt, wgt};
#pragma unroll
            for (int k = 0; k < 8; ++k) acc[k] = w2 * fs[k] + acc[k];
        }
        A0 = B0;
        A1 = B1;
        p += 8;
    }
    z += __shfl_xor(z, 16);
    z += __shfl_xor(z, 32);
#pragma unroll
    for (int k = 0; k < 8; ++k) {
        acc[k].x += __shfl_xor(acc[k].x, 16);
        acc[k].x += __shfl_xor(acc[k].x, 32);
        acc[k].y += __shfl_xor(acc[k].y, 16);
        acc[k].y += __shfl_xor(acc[k].y, 32);
    }
    if (j < 2) {
        float invz = 1.f / z;
        float o[8];
#pragma unroll
        for (int k = 0; k < 4; ++k) {
            int kk = j * 4 + k;
            o[2 * k]     = acc[kk].x * invz;
            o[2 * k + 1] = acc[kk].y * invz;
        }
        if (mode == 1) {
            uint4 rq = res[(long)n * 32 + 2 * l + j];
            const unsigned* ru = (const unsigned*)&rq;
#pragma unroll
            for (int k = 0; k < 4; ++k) {
                o[2 * k]     += __uint_as_float(ru[k] << 16);
                o[2 * k + 1] += __uint_as_float(ru[k] & 0xffff0000u);
            }
        }
        union { uint4 q; short s[8]; } ob;
#pragma unroll
        for (int k = 0; k < 8; ++k) {
            float v = o[k] > 0.f ? o[k] : (__expf(o[k]) - 1.f);
            ob.s[k] = f2b_raw(v);
        }
        out[(long)n * 32 + 2 * l + j] = ob.q;
    }
}

// ---------------- Fused final layer: 4 edge slots x 16 lanes, 2 dims/lane ----------
__global__ void k_gat_fused_fin(const unsigned* __restrict__ fr2u, const bf16* __restrict__ a2,
                                const int* __restrict__ rowptr, const int* __restrict__ csr_src,
                                void* __restrict__ outraw, int N, const int* __restrict__ flag) {
    int n = (blockIdx.x * blockDim.x + threadIdx.x) >> 6;
    int lane = threadIdx.x & 63;
    if (n >= N) return;
    int j = lane >> 4, l = lane & 15;

    unsigned fdu = fr2u[(long)n * 32 + l];
    unsigned au  = ((const unsigned*)a2)[l];
    f32x2 fd2, a6, a4;
    fd2.x = __uint_as_float(fdu << 16);
    fd2.y = __uint_as_float(fdu & 0xffff0000u);
    float ax = __uint_as_float(au << 16);
    float ay = __uint_as_float(au & 0xffff0000u);
    a6.x = 0.6f * ax; a6.y = 0.6f * ay;
    a4.x = 0.4f * ax; a4.y = 0.4f * ay;

    int p0 = rowptr[n], p1 = rowptr[n + 1];
    int iters = (p1 - p0 + 3) >> 2;
    float z = 0.f;
    f32x2 acc = {0.f, 0.f};

    int p = p0 + j;
    unsigned A0, A1, B0, B1;
    A0 = fr2u[(long)csr_src[p] * 32 + l];
    A1 = fr2u[(long)csr_src[p + 4] * 32 + l];
    for (int i = 0; i < iters; i += 2) {
        B0 = fr2u[(long)csr_src[p + 8] * 32 + l];
        B1 = fr2u[(long)csr_src[p + 12] * 32 + l];
#pragma unroll
        for (int half = 0; half < 2; ++half) {
            if (half == 1 && i + 1 >= iters) break;
            unsigned cu = half ? A1 : A0;
            int pp = p + half * 4;
            f32x2 fs;
            fs.x = __uint_as_float(cu << 16);
            fs.y = __uint_as_float(cu & 0xffff0000u);
            f32x2 u = fs + fd2;
            f32x2 ua;
            ua.x = __uint_as_float(__float_as_uint(u.x) & 0x7fffffffu);
            ua.y = __uint_as_float(__float_as_uint(u.y) & 0x7fffffffu);
            f32x2 t2 = a6 * u + a4 * ua;
            float t = t2.x + t2.y;
            t += __shfl_xor(t, 1);
            t += __shfl_xor(t, 2);
            t += __shfl_xor(t, 4);
            t += __shfl_xor(t, 8);
            float wgt = (pp < p1) ? __expf(t) : 0.f;
            z += wgt;
            f32x2 w2 = {wgt, wgt};
            acc = w2 * fs + acc;
        }
        A0 = B0;
        A1 = B1;
        p += 8;
    }
    z += __shfl_xor(z, 16);
    z += __shfl_xor(z, 32);
    acc.x += __shfl_xor(acc.x, 16);
    acc.x += __shfl_xor(acc.x, 32);
    acc.y += __shfl_xor(acc.y, 16);
    acc.y += __shfl_xor(acc.y, 32);
    if (j == 0) {
        unsigned ru = fr2u[(long)n * 32 + 16 + l];
        float invz = 1.f / z;
        float o0 = acc.x * invz + __uint_as_float(ru << 16);
        float o1 = acc.y * invz + __uint_as_float(ru & 0xffff0000u);
        if (*flag) {
            float2 ov = {o0, o1};
            ((float2*)outraw)[(long)n * 16 + l] = ov;
        } else {
            unsigned ob = ((unsigned)(unsigned short)f2b_raw(o0)) |
                          (((unsigned)(unsigned short)f2b_raw(o1)) << 16);
            ((unsigned*)outraw)[(long)n * 16 + l] = ob;
        }
    }
}

extern "C" void kernel_launch(void* const* d_in, const int* in_sizes, int n_in,
                              void* d_out, int out_size, void* d_ws, size_t ws_size,
                              hipStream_t stream) {
    const int N = in_sizes[0] / 256;
    const int E = in_sizes[1];

    const void* x   = d_in[0];
    const int*  src = (const int*)d_in[1];
    const int*  dst = (const int*)d_in[2];

    // ---- workspace carve ----
    char* w = (char*)d_ws;
    auto alloc = [&](size_t bytes) -> char* {
        char* p = w;
        w += (bytes + 15) & ~(size_t)15;
        return p;
    };
    bf16* buf0 = (bf16*)alloc((size_t)N * 256 * 2);  // hB
    bf16* buf1 = (bf16*)alloc((size_t)N * 256 * 2);  // hA
    bf16* buf2 = (bf16*)alloc((size_t)N * 256 * 2);  // fB / fr2
    int* csr_src = (int*)alloc((size_t)(E + 32) * 4);
    int* rowptr  = (int*)alloc((size_t)(N + 1) * 4);
    int* cursor  = (int*)alloc((size_t)N * 4);
    int* cnt     = (int*)alloc((size_t)N * 4);
    int* bsum    = (int*)alloc((size_t)128 * 4);
    int* bscan   = (int*)alloc((size_t)128 * 4);
    bf16* W0p  = (bf16*)alloc((size_t)65536 * 2);
    bf16* W1p  = (bf16*)alloc((size_t)65536 * 2);
    bf16* W2fp = (bf16*)alloc((size_t)64 * 256 * 2);
    bf16* a0c  = (bf16*)alloc((size_t)256 * 2);
    bf16* a1c  = (bf16*)alloc((size_t)256 * 2);
    bf16* a2c  = (bf16*)alloc((size_t)32 * 2);
    int*  flag = (int*)alloc(16);
    int*  ticket = (int*)alloc(16);
    int*  done = (int*)alloc(16);

    bf16* hA  = buf1;
    bf16* fB  = buf2;
    bf16* hB  = buf0;
    bf16* fr2 = buf2;

    // ---- cnt zero, then merged prep (flag + weights + hist + ticket/done zero) ----
    hipMemsetAsync(cnt, 0, (size_t)N * 4, stream);
    int prepN = 147456 + 544;
    if (prepN < E) prepN = E;
    k_prep<<<(prepN + 255) / 256, 256, 0, stream>>>(
        x, d_in[3], d_in[5], d_in[7], d_in[9], d_in[4], d_in[6], d_in[8],
        W0p, W1p, W2fp, a0c, a1c, a2c, flag, ticket, done, dst, cnt, E);

    // ---- CSR build: fused scan (co-resident decoupled) + scatter ----
    const int B = (N + 1023) / 1024;
    k_scan_fused<<<B, 256, 0, stream>>>(cnt, bsum, bscan, ticket, done, rowptr, cursor, N, E, B);
    k_scatter<<<(E + 255) / 256, 256, 0, stream>>>(src, dst, cursor, csr_src, E);

    const int ngrid4 = (int)(((long)N * 64 + 255) / 256);

    // ---- layer 0 (x read directly, fp32 converted in-flight) ----
    k_gemm_mfma<1><<<(N + 63) / 64, 256, 0, stream>>>(x, W0p, fB, N, flag);
    k_gat_fused<<<ngrid4, 256, 0, stream>>>((const uint4*)fB, a0c, rowptr, csr_src,
                                            nullptr, (uint4*)hA, N, 0);
    // ---- layer 1 (hA is ALWAYS bf16 -> non-adaptive) ----
    k_gemm_mfma<0><<<(N + 63) / 64, 256, 0, stream>>>(hA, W1p, fB, N, flag);
    k_gat_fused<<<ngrid4, 256, 0, stream>>>((const uint4*)fB, a1c, rowptr, csr_src,
                                            (const uint4*)hA, (uint4*)hB, N, 1);
    // ---- final layer ----
    k_gemm_mfma64<<<(N + 127) / 128, 256, 0, stream>>>(hB, W2fp, fr2, N);
    k_gat_fused_fin<<<ngrid4, 256, 0, stream>>>((const unsigned*)fr2, a2c, rowptr, csr_src,
                                                d_out, N, flag);
}

// Round 13
// 415.646 us; speedup vs baseline: 1.0630x; 1.0630x over previous
//
#include <hip/hip_runtime.h>
#include <hip/hip_bf16.h>

typedef __hip_bfloat16 bf16;
#define SLOPE 0.2f

__device__ __forceinline__ float b2f(bf16 v) { return __bfloat162float(v); }
__device__ __forceinline__ short f2b_raw(float x) {
    bf16 b = __float2bfloat16(x);
    return *reinterpret_cast<short*>(&b);
}

typedef __attribute__((ext_vector_type(8))) short bf16x8;
typedef __attribute__((ext_vector_type(16))) float f32x16;
typedef __attribute__((ext_vector_type(2))) float f32x2;

union Q16 { uint4 q[2]; unsigned u[8]; };

// ---------------- merged prep: per-block dtype detect, weight pack, cnt zero, ticket zero ----
__global__ void k_prep(const void* __restrict__ x,
                       const void* __restrict__ W0, const void* __restrict__ W1,
                       const void* __restrict__ W2, const void* __restrict__ Wr2,
                       const void* __restrict__ a0, const void* __restrict__ a1,
                       const void* __restrict__ a2, bf16* __restrict__ W0p,
                       bf16* __restrict__ W1p, bf16* __restrict__ W2fp,
                       bf16* __restrict__ a0c, bf16* __restrict__ a1c,
                       bf16* __restrict__ a2c, int* __restrict__ flag,
                       int* __restrict__ cnt, int* __restrict__ ticket, int N) {
    __shared__ int sflag;
    if (threadIdx.x < 64) {
        const unsigned short* u = (const unsigned short*)x;
        int tid = threadIdx.x;
        int nice = 0;
        for (int k = tid; k < 256; k += 64) {
            unsigned int bits = ((unsigned int)u[2 * k]) << 16;
            float v = __uint_as_float(bits);
            float av = fabsf(v);
            if (v == 0.0f || (av > 1e-6f && av < 100.0f)) ++nice;
        }
        for (int off = 32; off > 0; off >>= 1) nice += __shfl_down(nice, off, 64);
        if (tid == 0) sflag = (nice >= 192) ? 0 : 1;
    }
    __syncthreads();
    int isf = sflag;
    int idx = blockIdx.x * blockDim.x + threadIdx.x;
    if (blockIdx.x == 0 && threadIdx.x == 0) { *flag = isf; *ticket = 0; }
    if (idx < N) cnt[idx] = 0;
    if (idx < 131072) {
        int t = idx & 65535;
        int j = t & 7, L = (t >> 3) & 63, kt = (t >> 9) & 15, nt = t >> 13;
        int n = nt * 32 + (L & 31);
        int k = kt * 16 + (L >> 5) * 8 + j;
        const void* src = (idx < 65536) ? W0 : W1;
        float v = isf ? ((const float*)src)[k * 256 + n] : b2f(((const bf16*)src)[k * 256 + n]);
        bf16* dstp = (idx < 65536) ? W0p : W1p;
        dstp[t] = __float2bfloat16(v);
    } else if (idx < 147456) {
        int t = idx - 131072;
        int j = t & 7, L = (t >> 3) & 63, kt = (t >> 9) & 15, nt = t >> 13;
        int n = nt * 32 + (L & 31);
        int k = kt * 16 + (L >> 5) * 8 + j;
        const void* src = (n < 32) ? W2 : Wr2;
        int nn = n & 31;
        float v = isf ? ((const float*)src)[k * 32 + nn] : b2f(((const bf16*)src)[k * 32 + nn]);
        W2fp[t] = __float2bfloat16(v);
    } else if (idx < 147456 + 256) {
        int t = idx - 147456;
        float v = isf ? ((const float*)a0)[t] : b2f(((const bf16*)a0)[t]);
        a0c[t] = __float2bfloat16(v);
    } else if (idx < 147456 + 512) {
        int t = idx - 147456 - 256;
        float v = isf ? ((const float*)a1)[t] : b2f(((const bf16*)a1)[t]);
        a1c[t] = __float2bfloat16(v);
    } else if (idx < 147456 + 544) {
        int t = idx - 147456 - 512;
        float v = isf ? ((const float*)a2)[t] : b2f(((const bf16*)a2)[t]);
        a2c[t] = __float2bfloat16(v);
    }
}

// ---------------- CSR build ----------------
__global__ void k_hist(const int* __restrict__ dst, int* __restrict__ cnt, int E) {
    int e = blockIdx.x * blockDim.x + threadIdx.x;
    if (e < E) atomicAdd(&cnt[dst[e]], 1);
}

// per-block sums + last-block exclusive scan of the B partials (B <= 64)
__global__ void k_bsum_scan(const int* __restrict__ cnt, int* __restrict__ bsum,
                            int* __restrict__ ticket, int n, int B) {
    __shared__ int sh[256];
    __shared__ int lastFlag;
    int base = blockIdx.x * 1024 + threadIdx.x * 4;
    int s = 0;
#pragma unroll
    for (int k = 0; k < 4; ++k) { int i = base + k; if (i < n) s += cnt[i]; }
    sh[threadIdx.x] = s;
    __syncthreads();
    for (int off = 128; off > 0; off >>= 1) {
        if (threadIdx.x < off) sh[threadIdx.x] += sh[threadIdx.x + off];
        __syncthreads();
    }
    if (threadIdx.x == 0) {
        atomicExch(&bsum[blockIdx.x], sh[0]);
        __threadfence();
        int t = atomicAdd(ticket, 1);
        lastFlag = (t == B - 1) ? 1 : 0;
    }
    __syncthreads();
    if (lastFlag && threadIdx.x < 64) {
        int tid = threadIdx.x;
        int v = (tid < B) ? atomicAdd(&bsum[tid], 0) : 0;
        int xv = v;
#pragma unroll
        for (int off = 1; off < 64; off <<= 1) {
            int y = __shfl_up(xv, off, 64);
            if (tid >= off) xv += y;
        }
        if (tid < B) bsum[tid] = xv - v;
    }
}

__global__ void k_scanwrite(const int* __restrict__ cnt, const int* __restrict__ bsum,
                            int* __restrict__ rowptr, int* __restrict__ cursor, int n, int E) {
    __shared__ int sh[256];
    int base = blockIdx.x * 1024 + threadIdx.x * 4;
    int loc[4];
    int s = 0;
#pragma unroll
    for (int k = 0; k < 4; ++k) {
        int i = base + k;
        loc[k] = (i < n) ? cnt[i] : 0;
        s += loc[k];
    }
    sh[threadIdx.x] = s;
    __syncthreads();
    for (int off = 1; off < 256; off <<= 1) {
        int u = (threadIdx.x >= off) ? sh[threadIdx.x - off] : 0;
        __syncthreads();
        sh[threadIdx.x] += u;
        __syncthreads();
    }
    int run = bsum[blockIdx.x] + sh[threadIdx.x] - s;
#pragma unroll
    for (int k = 0; k < 4; ++k) {
        int i = base + k;
        if (i < n) { rowptr[i] = run; cursor[i] = run; run += loc[k]; }
    }
    if (blockIdx.x == 0 && threadIdx.x == 0) rowptr[n] = E;
}

__global__ void k_scatter(const int* __restrict__ src, const int* __restrict__ dst,
                          int* __restrict__ cursor, int* __restrict__ csr_src, int E) {
    int e = blockIdx.x * blockDim.x + threadIdx.x;
    if (e < E) {
        int p = atomicAdd(&cursor[dst[e]], 1);
        csr_src[p] = src[e];
    }
}

// ---------------- MFMA GEMM with LDS-staged A: C[N,256](bf16) = A[N,256] @ W ----
// Block = 64 rows x 256 cols; A-tile (64x512B) staged via coalesced 16B/lane loads.
// LDS row stride 264 shorts (+8 pad -> max 4-way read conflict).
template <int ADAPT>
__global__ void k_gemm_mfma(const void* __restrict__ A, const bf16* __restrict__ Wp,
                            bf16* __restrict__ C, int Nrows, const int* __restrict__ flag) {
    __shared__ short sA[64 * 264];
    int tid = threadIdx.x;
    int warp = tid >> 6;
    int lane = tid & 63;
    long blockRow = (long)blockIdx.x * 64;
    int isf32 = ADAPT ? *flag : 0;

    if (ADAPT && isf32) {
        const float* Af = (const float*)A;
#pragma unroll
        for (int it = 0; it < 16; ++it) {
            int linear = it * 256 + tid;   // float4 index; 64 per row
            int row = linear >> 6;
            int col4 = linear & 63;
            long gr = blockRow + row;
            if (gr > Nrows - 1) gr = Nrows - 1;
            float4 v = ((const float4*)(Af + gr * 256))[col4];
            short* d = &sA[row * 264 + col4 * 4];
            d[0] = f2b_raw(v.x); d[1] = f2b_raw(v.y);
            d[2] = f2b_raw(v.z); d[3] = f2b_raw(v.w);
        }
    } else {
        const short* Ab = (const short*)A;
#pragma unroll
        for (int it = 0; it < 8; ++it) {
            int linear = it * 256 + tid;   // 16B chunk index; 32 per row
            int row = linear >> 5;
            int c8 = linear & 31;
            long gr = blockRow + row;
            if (gr > Nrows - 1) gr = Nrows - 1;
            bf16x8 v = *(const bf16x8*)(Ab + gr * 256 + c8 * 8);
            *(bf16x8*)&sA[row * 264 + c8 * 8] = v;
        }
    }
    __syncthreads();

    int wr = warp >> 1;
    int wc = warp & 1;
    long rowBase = blockRow + wr * 32;
    int colBase = wc * 128;
    int m = lane & 31;
    int g = lane >> 5;
    const short* Wps = (const short*)Wp;
    int smemRow = wr * 32 + m;
    f32x16 acc[4] = {};
    for (int kt = 0; kt < 16; ++kt) {
        bf16x8 af = *(const bf16x8*)&sA[smemRow * 264 + kt * 16 + g * 8];
#pragma unroll
        for (int ct = 0; ct < 4; ++ct) {
            int nt = wc * 4 + ct;
            bf16x8 bfr = *(const bf16x8*)(Wps + (((nt << 4) + kt) << 9) + lane * 8);
            acc[ct] = __builtin_amdgcn_mfma_f32_32x32x16_bf16(af, bfr, acc[ct], 0, 0, 0);
        }
    }
#pragma unroll
    for (int ct = 0; ct < 4; ++ct) {
#pragma unroll
        for (int i = 0; i < 16; ++i) {
            long row = rowBase + (i & 3) + 8 * (i >> 2) + 4 * g;
            if (row < Nrows)
                C[row * 256 + colBase + ct * 32 + m] = __float2bfloat16(acc[ct][i]);
        }
    }
}

// C[N,64] = A[N,256](bf16) @ combined final weights (fragment-packed)
__global__ void k_gemm_mfma64(const bf16* __restrict__ A, const bf16* __restrict__ Wp,
                              bf16* __restrict__ C, int Nrows) {
    int warp = threadIdx.x >> 6;
    int lane = threadIdx.x & 63;
    long rowBase = (long)blockIdx.x * 128 + warp * 32;
    int m = lane & 31;
    int g = lane >> 5;
    long r = rowBase + m;
    if (r >= Nrows) r = Nrows - 1;
    const short* Arow = (const short*)A + r * 256 + g * 8;
    const short* Wps = (const short*)Wp;
    f32x16 acc[2] = {};
    for (int kt = 0; kt < 16; ++kt) {
        bf16x8 af = *(const bf16x8*)(Arow + kt * 16);
#pragma unroll
        for (int ct = 0; ct < 2; ++ct) {
            bf16x8 bfr = *(const bf16x8*)(Wps + (((ct << 4) + kt) << 9) + lane * 8);
            acc[ct] = __builtin_amdgcn_mfma_f32_32x32x16_bf16(af, bfr, acc[ct], 0, 0, 0);
        }
    }
#pragma unroll
    for (int ct = 0; ct < 2; ++ct) {
#pragma unroll
        for (int i = 0; i < 16; ++i) {
            long row = rowBase + (i & 3) + 8 * (i >> 2) + 4 * g;
            if (row < Nrows)
                C[row * 64 + ct * 32 + m] = __float2bfloat16(acc[ct][i]);
        }
    }
}

// ---------------- Fused GATv2 layer: 8 edges/iter (2 per slot), 16 lanes/edge ----------
// Round-11 proven body (clamped prefetch, 64 VGPR, no LDS).
__global__ void k_gat_fused(const uint4* __restrict__ f, const bf16* __restrict__ a,
                            const int* __restrict__ rowptr, const int* __restrict__ csr_src,
                            const uint4* __restrict__ res, uint4* __restrict__ out,
                            int N, int mode) {
    int n = (blockIdx.x * blockDim.x + threadIdx.x) >> 6;
    int lane = threadIdx.x & 63;
    if (n >= N) return;
    int j = lane >> 4, l = lane & 15;

    Q16 fdq, aq;
    fdq.q[0] = f[(long)n * 32 + 2 * l];
    fdq.q[1] = f[(long)n * 32 + 2 * l + 1];
    aq.q[0] = ((const uint4*)a)[2 * l];
    aq.q[1] = ((const uint4*)a)[2 * l + 1];
    f32x2 fd2[8], a6[8], a4[8];
#pragma unroll
    for (int i = 0; i < 8; ++i) {
        f32x2 fv, av;
        fv.x = __uint_as_float(fdq.u[i] << 16);
        fv.y = __uint_as_float(fdq.u[i] & 0xffff0000u);
        av.x = __uint_as_float(aq.u[i] << 16);
        av.y = __uint_as_float(aq.u[i] & 0xffff0000u);
        fd2[i] = fv;
        a6[i] = 0.6f * av;
        a4[i] = 0.4f * av;
    }

    int p0 = rowptr[n], p1 = rowptr[n + 1];
    int iters = (p1 - p0 + 3) >> 2;
    float z = 0.f;
    f32x2 acc[8] = {};

    int p = p0 + j;
    int pc = p1 - 1;
    Q16 A0, A1, B0, B1;
    {
        int s0 = csr_src[min(p, pc)];
        A0.q[0] = f[(long)s0 * 32 + 2 * l];
        A0.q[1] = f[(long)s0 * 32 + 2 * l + 1];
        int s1 = csr_src[min(p + 4, pc)];
        A1.q[0] = f[(long)s1 * 32 + 2 * l];
        A1.q[1] = f[(long)s1 * 32 + 2 * l + 1];
    }
    for (int i = 0; i < iters; i += 2) {
        int s0 = csr_src[min(p + 8, pc)];
        B0.q[0] = f[(long)s0 * 32 + 2 * l];
        B0.q[1] = f[(long)s0 * 32 + 2 * l + 1];
        int s1 = csr_src[min(p + 12, pc)];
        B1.q[0] = f[(long)s1 * 32 + 2 * l];
        B1.q[1] = f[(long)s1 * 32 + 2 * l + 1];

#pragma unroll
        for (int half = 0; half < 2; ++half) {
            if (half == 1 && i + 1 >= iters) break;
            const Q16& cur = half ? A1 : A0;
            int pp = p + half * 4;
            f32x2 fs[8];
            f32x2 t2 = {0.f, 0.f};
#pragma unroll
            for (int k = 0; k < 8; ++k) {
                f32x2 fv;
                fv.x = __uint_as_float(cur.u[k] << 16);
                fv.y = __uint_as_float(cur.u[k] & 0xffff0000u);
                fs[k] = fv;
                f32x2 u = fv + fd2[k];
                f32x2 ua;
                ua.x = __uint_as_float(__float_as_uint(u.x) & 0x7fffffffu);
                ua.y = __uint_as_float(__float_as_uint(u.y) & 0x7fffffffu);
                t2 = a6[k] * u + t2;
                t2 = a4[k] * ua + t2;
            }
            float t = t2.x + t2.y;
            t += __shfl_xor(t, 1);
            t += __shfl_xor(t, 2);
            float wgt = (pp < p1) ? __expf(t) : 0.f;
            z += wgt;
            f32x2 w2 = {wgt, wgt};
#pragma unroll
            for (int k = 0; k < 8; ++k) acc[k] = w2 * fs[k] + acc[k];
        }
        A0 = B0;
        A1 = B1;
        p += 8;
    }
    z += __shfl_xor(z, 16);
    z += __shfl_xor(z, 32);
#pragma unroll
    for (int k = 0; k < 8; ++k) {
        acc[k].x += __shfl_xor(acc[k].x, 16);
        acc[k].x += __shfl_xor(acc[k].x, 32);
        acc[k].y += __shfl_xor(acc[k].y, 16);
        acc[k].y += __shfl_xor(acc[k].y, 32);
    }
    if (j < 2) {
        float invz = 1.f / z;
        float o[8];
#pragma unroll
        for (int k = 0; k < 4; ++k) {
            int kk = j * 4 + k;
            o[2 * k]     = acc[kk].x * invz;
            o[2 * k + 1] = acc[kk].y * invz;
        }
        if (mode == 1) {
            uint4 rq = res[(long)n * 32 + 2 * l + j];
            const unsigned* ru = (const unsigned*)&rq;
#pragma unroll
            for (int k = 0; k < 4; ++k) {
                o[2 * k]     += __uint_as_float(ru[k] << 16);
                o[2 * k + 1] += __uint_as_float(ru[k] & 0xffff0000u);
            }
        }
        union { uint4 q; short s[8]; } ob;
#pragma unroll
        for (int k = 0; k < 8; ++k) {
            float v = o[k] > 0.f ? o[k] : (__expf(o[k]) - 1.f);
            ob.s[k] = f2b_raw(v);
        }
        out[(long)n * 32 + 2 * l + j] = ob.q;
    }
}

// ---------------- Fused final layer: 4 edge slots x 16 lanes, 2 dims/lane ----------
__global__ void k_gat_fused_fin(const unsigned* __restrict__ fr2u, const bf16* __restrict__ a2,
                                const int* __restrict__ rowptr, const int* __restrict__ csr_src,
                                void* __restrict__ outraw, int N, const int* __restrict__ flag) {
    int n = (blockIdx.x * blockDim.x + threadIdx.x) >> 6;
    int lane = threadIdx.x & 63;
    if (n >= N) return;
    int j = lane >> 4, l = lane & 15;

    unsigned fdu = fr2u[(long)n * 32 + l];
    unsigned au  = ((const unsigned*)a2)[l];
    f32x2 fd2, a6, a4;
    fd2.x = __uint_as_float(fdu << 16);
    fd2.y = __uint_as_float(fdu & 0xffff0000u);
    float ax = __uint_as_float(au << 16);
    float ay = __uint_as_float(au & 0xffff0000u);
    a6.x = 0.6f * ax; a6.y = 0.6f * ay;
    a4.x = 0.4f * ax; a4.y = 0.4f * ay;

    int p0 = rowptr[n], p1 = rowptr[n + 1];
    int iters = (p1 - p0 + 3) >> 2;
    float z = 0.f;
    f32x2 acc = {0.f, 0.f};

    int p = p0 + j;
    int pc = p1 - 1;
    unsigned A0, A1, B0, B1;
    A0 = fr2u[(long)csr_src[min(p, pc)] * 32 + l];
    A1 = fr2u[(long)csr_src[min(p + 4, pc)] * 32 + l];
    for (int i = 0; i < iters; i += 2) {
        B0 = fr2u[(long)csr_src[min(p + 8, pc)] * 32 + l];
        B1 = fr2u[(long)csr_src[min(p + 12, pc)] * 32 + l];
#pragma unroll
        for (int half = 0; half < 2; ++half) {
            if (half == 1 && i + 1 >= iters) break;
            unsigned cu = half ? A1 : A0;
            int pp = p + half * 4;
            f32x2 fs;
            fs.x = __uint_as_float(cu << 16);
            fs.y = __uint_as_float(cu & 0xffff0000u);
            f32x2 u = fs + fd2;
            f32x2 ua;
            ua.x = __uint_as_float(__float_as_uint(u.x) & 0x7fffffffu);
            ua.y = __uint_as_float(__float_as_uint(u.y) & 0x7fffffffu);
            f32x2 t2 = a6 * u + a4 * ua;
            float t = t2.x + t2.y;
            t += __shfl_xor(t, 1);
            t += __shfl_xor(t, 2);
            t += __shfl_xor(t, 4);
            t += __shfl_xor(t, 8);
            float wgt = (pp < p1) ? __expf(t) : 0.f;
            z += wgt;
            f32x2 w2 = {wgt, wgt};
            acc = w2 * fs + acc;
        }
        A0 = B0;
        A1 = B1;
        p += 8;
    }
    z += __shfl_xor(z, 16);
    z += __shfl_xor(z, 32);
    acc.x += __shfl_xor(acc.x, 16);
    acc.x += __shfl_xor(acc.x, 32);
    acc.y += __shfl_xor(acc.y, 16);
    acc.y += __shfl_xor(acc.y, 32);
    if (j == 0) {
        unsigned ru = fr2u[(long)n * 32 + 16 + l];
        float invz = 1.f / z;
        float o0 = acc.x * invz + __uint_as_float(ru << 16);
        float o1 = acc.y * invz + __uint_as_float(ru & 0xffff0000u);
        if (*flag) {
            float2 ov = {o0, o1};
            ((float2*)outraw)[(long)n * 16 + l] = ov;
        } else {
            unsigned ob = ((unsigned)(unsigned short)f2b_raw(o0)) |
                          (((unsigned)(unsigned short)f2b_raw(o1)) << 16);
            ((unsigned*)outraw)[(long)n * 16 + l] = ob;
        }
    }
}

extern "C" void kernel_launch(void* const* d_in, const int* in_sizes, int n_in,
                              void* d_out, int out_size, void* d_ws, size_t ws_size,
                              hipStream_t stream) {
    const int N = in_sizes[0] / 256;
    const int E = in_sizes[1];

    const void* x   = d_in[0];
    const int*  src = (const int*)d_in[1];
    const int*  dst = (const int*)d_in[2];

    // ---- workspace carve ----
    char* w = (char*)d_ws;
    auto alloc = [&](size_t bytes) -> char* {
        char* p = w;
        w += (bytes + 15) & ~(size_t)15;
        return p;
    };
    bf16* buf0 = (bf16*)alloc((size_t)N * 256 * 2);  // hB
    bf16* buf1 = (bf16*)alloc((size_t)N * 256 * 2);  // hA
    bf16* buf2 = (bf16*)alloc((size_t)N * 256 * 2);  // fB / fr2
    int* csr_src = (int*)alloc((size_t)E * 4);
    int* rowptr  = (int*)alloc((size_t)(N + 1) * 4);
    int* cursor  = (int*)alloc((size_t)N * 4);
    int* cnt     = (int*)alloc((size_t)N * 4);
    int* bsum    = (int*)alloc((size_t)1024 * 4);
    bf16* W0p  = (bf16*)alloc((size_t)65536 * 2);
    bf16* W1p  = (bf16*)alloc((size_t)65536 * 2);
    bf16* W2fp = (bf16*)alloc((size_t)64 * 256 * 2);
    bf16* a0c  = (bf16*)alloc((size_t)256 * 2);
    bf16* a1c  = (bf16*)alloc((size_t)256 * 2);
    bf16* a2c  = (bf16*)alloc((size_t)32 * 2);
    int*  flag = (int*)alloc(16);
    int*  ticket = (int*)alloc(16);

    bf16* hA  = buf1;
    bf16* fB  = buf2;
    bf16* hB  = buf0;
    bf16* fr2 = buf2;

    // ---- merged prep (flag + weights + cnt zero + ticket zero) ----
    int prepN = 147456 + 544;
    if (prepN < N) prepN = N;
    k_prep<<<(prepN + 255) / 256, 256, 0, stream>>>(
        x, d_in[3], d_in[5], d_in[7], d_in[9], d_in[4], d_in[6], d_in[8],
        W0p, W1p, W2fp, a0c, a1c, a2c, flag, cnt, ticket, N);

    // ---- CSR build ----
    const int B = (N + 1023) / 1024;
    k_hist<<<(E + 255) / 256, 256, 0, stream>>>(dst, cnt, E);
    k_bsum_scan<<<B, 256, 0, stream>>>(cnt, bsum, ticket, N, B);
    k_scanwrite<<<B, 256, 0, stream>>>(cnt, bsum, rowptr, cursor, N, E);
    k_scatter<<<(E + 255) / 256, 256, 0, stream>>>(src, dst, cursor, csr_src, E);

    const int ngrid4 = (int)(((long)N * 64 + 255) / 256);

    // ---- layer 0 (x read directly, fp32 converted during LDS staging) ----
    k_gemm_mfma<1><<<(N + 63) / 64, 256, 0, stream>>>(x, W0p, fB, N, flag);
    k_gat_fused<<<ngrid4, 256, 0, stream>>>((const uint4*)fB, a0c, rowptr, csr_src,
                                            nullptr, (uint4*)hA, N, 0);
    // ---- layer 1 (hA is ALWAYS bf16 -> non-adaptive) ----
    k_gemm_mfma<0><<<(N + 63) / 64, 256, 0, stream>>>(hA, W1p, fB, N, flag);
    k_gat_fused<<<ngrid4, 256, 0, stream>>>((const uint4*)fB, a1c, rowptr, csr_src,
                                            (const uint4*)hA, (uint4*)hB, N, 1);
    // ---- final layer ----
    k_gemm_mfma64<<<(N + 127) / 128, 256, 0, stream>>>(hB, W2fp, fr2, N);
    k_gat_fused_fin<<<ngrid4, 256, 0, stream>>>((const unsigned*)fr2, a2c, rowptr, csr_src,
                                                d_out, N, flag);
}